// Round 1
// baseline (24186.424 us; speedup 1.0000x reference)
//
#include <hip/hip_runtime.h>
#include <cstddef>

#define BB    4
#define NN    10000
#define EE    160000
#define BN    40000      // BB*NN
#define HISTC 8
#define PREDC 12
#define TSTEP 20         // HIST+PRED
#define FEX   8
#define HIDC  64
#define EHID  32
#define EOUTC 30
#define GOUTC 13
#define GINC  22         // GOUTC + 9

__device__ __forceinline__ float sigm(float x) {
    return 1.0f / (1.0f + __expf(-x));
}
__device__ __forceinline__ float tanh_fast(float x) {
    x = fminf(fmaxf(x, -15.0f), 15.0f);
    float e = __expf(2.0f * x);
    return (e - 1.0f) / (e + 1.0f);
}

// ---------------- edge_attr normalization stats (mean, 1/std ddof=1) ----------
__global__ void stats_kernel(const float* __restrict__ ea, float* __restrict__ stats) {
    __shared__ double sm[256][4];
    double s0 = 0, s1 = 0, q0 = 0, q1 = 0;
    for (int e = threadIdx.x; e < EE; e += 256) {
        float2 v = reinterpret_cast<const float2*>(ea)[e];
        double v0 = (double)v.x, v1 = (double)v.y;
        s0 += v0; q0 += v0 * v0;
        s1 += v1; q1 += v1 * v1;
    }
    sm[threadIdx.x][0] = s0; sm[threadIdx.x][1] = s1;
    sm[threadIdx.x][2] = q0; sm[threadIdx.x][3] = q1;
    __syncthreads();
    for (int off = 128; off > 0; off >>= 1) {
        if (threadIdx.x < off) {
            for (int k = 0; k < 4; k++) sm[threadIdx.x][k] += sm[threadIdx.x + off][k];
        }
        __syncthreads();
    }
    if (threadIdx.x == 0) {
        double m0 = sm[0][0] / EE, m1 = sm[0][1] / EE;
        double v0 = (sm[0][2] - sm[0][0] * sm[0][0] / EE) / (double)(EE - 1);
        double v1 = (sm[0][3] - sm[0][1] * sm[0][1] / EE) / (double)(EE - 1);
        float sd0 = fmaxf((float)sqrt(v0 > 0 ? v0 : 0.0), 1e-6f);
        float sd1 = fmaxf((float)sqrt(v1 > 0 ? v1 : 0.0), 1e-6f);
        stats[0] = (float)m0; stats[1] = (float)m1;
        stats[2] = 1.0f / sd0; stats[3] = 1.0f / sd1;
    }
}

// ---------------- per-edge precompute: ean0, ean1, dist, direc ----------------
__global__ void edgepre_kernel(const float* __restrict__ ea, const float* __restrict__ stats,
                               float* __restrict__ epre) {
    int e = blockIdx.x * 256 + threadIdx.x;
    if (e >= EE) return;
    float2 v = reinterpret_cast<const float2*>(ea)[e];
    float4 r;
    r.x = (v.x - stats[0]) * stats[2];
    r.y = (v.y - stats[1]) * stats[3];
    r.z = fmaxf(v.x, 1e-3f);   // city_dist
    r.w = v.y;                 // city_direc (raw)
    reinterpret_cast<float4*>(epre)[e] = r;
}

// ---------------- xn init from pm25_hist[:, -1] -------------------------------
__global__ void initxn_kernel(const float* __restrict__ pm, float* __restrict__ xn) {
    int i = blockIdx.x * 256 + threadIdx.x;
    if (i >= BN) return;
    int b = i / NN, n = i - b * NN;
    xn[i] = pm[(b * HISTC + (HISTC - 1)) * NN + n];
}

// ---------------- edge MLP + scatter-add --------------------------------------
// grid (EE/256, 2); blockIdx.y = bA; thread handles batches bA and bA+2.
__global__ __launch_bounds__(256) void edge_kernel(
    const float* __restrict__ xn, const float* __restrict__ feature, int t,
    const int* __restrict__ eidx, const float* __restrict__ epre,
    const float* __restrict__ ew1, const float* __restrict__ eb1,
    const float* __restrict__ ew2, const float* __restrict__ eb2,
    const float* __restrict__ wmean, const float* __restrict__ wstd,
    float* __restrict__ agg)
{
    __shared__ alignas(16) float w1p[EHID * 24];       // [o][k] padded to 24
    __shared__ alignas(16) float w2t[EOUTC * EHID];    // [o][k]
    __shared__ float b1s[EHID];
    __shared__ float b2s[EOUTC];
    for (int i = threadIdx.x; i < EHID * 21; i += 256) {
        int o = i / 21, k = i - o * 21;
        w1p[o * 24 + k] = ew1[k * EHID + o];
    }
    if (threadIdx.x < EHID) {
        w1p[threadIdx.x * 24 + 21] = 0.f;
        w1p[threadIdx.x * 24 + 22] = 0.f;
        w1p[threadIdx.x * 24 + 23] = 0.f;
        b1s[threadIdx.x] = eb1[threadIdx.x];
    }
    for (int i = threadIdx.x; i < EOUTC * EHID; i += 256) {
        int o = i / EHID, k = i - o * EHID;
        w2t[i] = ew2[k * EOUTC + o];
    }
    if (threadIdx.x < EOUTC) b2s[threadIdx.x] = eb2[threadIdx.x];
    __syncthreads();

    int e = blockIdx.x * 256 + threadIdx.x;
    if (e >= EE) return;
    int bA = blockIdx.y;
    int bB = bA + 2;
    int s = eidx[e];
    int g = eidx[EE + e];
    float4 ep = reinterpret_cast<const float4*>(epre)[e];
    float wm0 = wmean[0], wm1 = wmean[1];
    float sd0 = fmaxf(wstd[0], 1e-6f), sd1 = fmaxf(wstd[1], 1e-6f);

    float inA[21], inB[21];
    {
        const size_t fo = ((size_t)bA * TSTEP + HISTC + t) * NN;
        inA[0] = xn[bA * NN + s];
        const float4* fp = reinterpret_cast<const float4*>(feature + (fo + s) * FEX);
        float4 u = fp[0], v = fp[1];
        inA[1] = u.x; inA[2] = u.y; inA[3] = u.z; inA[4] = u.w;
        inA[5] = v.x; inA[6] = v.y; inA[7] = v.z; inA[8] = v.w;
        inA[9] = xn[bA * NN + g];
        const float4* fq = reinterpret_cast<const float4*>(feature + (fo + g) * FEX);
        float4 p = fq[0], q = fq[1];
        inA[10] = p.x; inA[11] = p.y; inA[12] = p.z; inA[13] = p.w;
        inA[14] = q.x; inA[15] = q.y; inA[16] = q.z; inA[17] = q.w;
    }
    {
        const size_t fo = ((size_t)bB * TSTEP + HISTC + t) * NN;
        inB[0] = xn[bB * NN + s];
        const float4* fp = reinterpret_cast<const float4*>(feature + (fo + s) * FEX);
        float4 u = fp[0], v = fp[1];
        inB[1] = u.x; inB[2] = u.y; inB[3] = u.z; inB[4] = u.w;
        inB[5] = v.x; inB[6] = v.y; inB[7] = v.z; inB[8] = v.w;
        inB[9] = xn[bB * NN + g];
        const float4* fq = reinterpret_cast<const float4*>(feature + (fo + g) * FEX);
        float4 p = fq[0], q = fq[1];
        inB[10] = p.x; inB[11] = p.y; inB[12] = p.z; inB[13] = p.w;
        inB[14] = q.x; inB[15] = q.y; inB[16] = q.z; inB[17] = q.w;
    }
    inA[18] = ep.x; inA[19] = ep.y;
    inB[18] = ep.x; inB[19] = ep.y;
    {
        float sp = fmaxf(inA[7] * sd0 + wm0, 0.f);
        float wd = (inA[8] * sd1 + wm1) * 0.017453292519943295f;
        float th = fabsf(ep.w - wd);
        inA[20] = fmaxf(3.f * sp * __cosf(th) / ep.z, 0.f);
    }
    {
        float sp = fmaxf(inB[7] * sd0 + wm0, 0.f);
        float wd = (inB[8] * sd1 + wm1) * 0.017453292519943295f;
        float th = fabsf(ep.w - wd);
        inB[20] = fmaxf(3.f * sp * __cosf(th) / ep.z, 0.f);
    }

    float h1A[EHID], h1B[EHID];
    #pragma unroll
    for (int o = 0; o < EHID; o++) {
        float a = b1s[o], b = b1s[o];
        const float4* wr = reinterpret_cast<const float4*>(&w1p[o * 24]);
        #pragma unroll
        for (int q = 0; q < 5; q++) {
            float4 w = wr[q];
            a += inA[4*q] * w.x + inA[4*q+1] * w.y + inA[4*q+2] * w.z + inA[4*q+3] * w.w;
            b += inB[4*q] * w.x + inB[4*q+1] * w.y + inB[4*q+2] * w.z + inB[4*q+3] * w.w;
        }
        float wl = w1p[o * 24 + 20];
        a += inA[20] * wl;
        b += inB[20] * wl;
        h1A[o] = sigm(a);
        h1B[o] = sigm(b);
    }

    size_t gA = (size_t)bA * NN + g, sA = (size_t)bA * NN + s;
    size_t gB = (size_t)bB * NN + g, sB = (size_t)bB * NN + s;
    for (int o = 0; o < EOUTC; o++) {
        float a = b2s[o], b = b2s[o];
        const float4* wr = reinterpret_cast<const float4*>(&w2t[o * EHID]);
        #pragma unroll
        for (int q = 0; q < 8; q++) {
            float4 w = wr[q];
            a += h1A[4*q] * w.x + h1A[4*q+1] * w.y + h1A[4*q+2] * w.z + h1A[4*q+3] * w.w;
            b += h1B[4*q] * w.x + h1B[4*q+1] * w.y + h1B[4*q+2] * w.z + h1B[4*q+3] * w.w;
        }
        float vA = sigm(a), vB = sigm(b);
        float* base = agg + (size_t)o * BN;
        atomicAdd(base + gA,  vA);
        atomicAdd(base + sA, -vA);
        atomicAdd(base + gB,  vB);
        atomicAdd(base + sB, -vB);
    }
}

// ---------------- node: gnn-out + GRU + fc ------------------------------------
// grid BN/64 blocks of 256: each block = 64 nodes; wave w handles hidden dims
// [w*16, w*16+16). Weight row index is wave-uniform -> scalar loads.
__global__ __launch_bounds__(256) void node_kernel(
    float* xnio, const float* __restrict__ feature, int t,
    const float* __restrict__ agg,
    const float* __restrict__ nw, const float* __restrict__ nb,
    const float* __restrict__ wi, const float* __restrict__ wh,
    const float* __restrict__ bi, const float* __restrict__ bh,
    const float* __restrict__ fw, const float* __restrict__ fb,
    float* __restrict__ hnbuf, float* __restrict__ out)
{
    __shared__ float xpart[4][64];
    int lane = threadIdx.x & 63;
    int wav  = threadIdx.x >> 6;
    int node = blockIdx.x * 64 + lane;
    int b = node / NN;
    int n = node - b * NN;

    // gnn output -> xc[0..12]
    float a[EOUTC];
    #pragma unroll
    for (int c = 0; c < EOUTC; c++) a[c] = agg[(size_t)c * BN + node];
    float xc[GINC];
    #pragma unroll
    for (int o = 0; o < GOUTC; o++) {
        float acc = nb[o];
        #pragma unroll
        for (int c = 0; c < EOUTC; c++) acc += a[c] * nw[c * GOUTC + o];
        xc[o] = sigm(acc);
    }
    xc[13] = xnio[node];
    {
        const float4* fp = reinterpret_cast<const float4*>(
            feature + (((size_t)b * TSTEP + HISTC + t) * NN + n) * FEX);
        float4 u = fp[0], v = fp[1];
        xc[14] = u.x; xc[15] = u.y; xc[16] = u.z; xc[17] = u.w;
        xc[18] = v.x; xc[19] = v.y; xc[20] = v.z; xc[21] = v.w;
    }

    float h[HIDC];
    #pragma unroll
    for (int k = 0; k < HIDC; k++) h[k] = hnbuf[(size_t)k * BN + node];
    // all waves must finish reading old h before any wave writes its planes
    __syncthreads();

    float xsum = 0.f;
    for (int jj = 0; jj < 16; jj++) {
        int j = wav * 16 + jj;   // wave-uniform
        float ir = bi[j], iz = bi[64 + j], in_ = bi[128 + j];
        const float* wr0 = wi + (size_t)j * GINC;
        const float* wr1 = wi + (size_t)(64 + j) * GINC;
        const float* wr2 = wi + (size_t)(128 + j) * GINC;
        #pragma unroll
        for (int k = 0; k < GINC; k++) {
            ir  += wr0[k] * xc[k];
            iz  += wr1[k] * xc[k];
            in_ += wr2[k] * xc[k];
        }
        float hr = bh[j], hz = bh[64 + j], hn_ = bh[128 + j];
        const float* vr0 = wh + (size_t)j * HIDC;
        const float* vr1 = wh + (size_t)(64 + j) * HIDC;
        const float* vr2 = wh + (size_t)(128 + j) * HIDC;
        #pragma unroll
        for (int k = 0; k < HIDC; k++) {
            hr  += vr0[k] * h[k];
            hz  += vr1[k] * h[k];
            hn_ += vr2[k] * h[k];
        }
        float r  = sigm(ir + hr);
        float z  = sigm(iz + hz);
        float nn = tanh_fast(in_ + r * hn_);
        float hold = hnbuf[(size_t)j * BN + node];  // own wave's plane only
        float hnew = (1.f - z) * nn + z * hold;
        hnbuf[(size_t)j * BN + node] = hnew;
        xsum += hnew * fw[j];
    }
    xpart[wav][lane] = xsum;
    __syncthreads();
    if (wav == 0) {
        float tot = xpart[0][lane] + xpart[1][lane] + xpart[2][lane] + xpart[3][lane] + fb[0];
        xnio[node] = tot;
        out[(size_t)node * PREDC + t] = tot;
    }
}

extern "C" void kernel_launch(void* const* d_in, const int* in_sizes, int n_in,
                              void* d_out, int out_size, void* d_ws, size_t ws_size,
                              hipStream_t stream)
{
    const float* pm    = (const float*)d_in[0];
    const float* feat  = (const float*)d_in[1];
    const float* ea    = (const float*)d_in[2];
    const float* wmean = (const float*)d_in[3];
    const float* wstd  = (const float*)d_in[4];
    const float* ew1   = (const float*)d_in[5];
    const float* eb1   = (const float*)d_in[6];
    const float* ew2   = (const float*)d_in[7];
    const float* eb2   = (const float*)d_in[8];
    const float* nw    = (const float*)d_in[9];
    const float* nb    = (const float*)d_in[10];
    const float* wi    = (const float*)d_in[11];
    const float* wh    = (const float*)d_in[12];
    const float* bi    = (const float*)d_in[13];
    const float* bh    = (const float*)d_in[14];
    const float* fw    = (const float*)d_in[15];
    const float* fb    = (const float*)d_in[16];
    const int*   eidx  = (const int*)d_in[17];
    float* out = (float*)d_out;
    float* ws  = (float*)d_ws;

    float* stats = ws;                          // 16 floats (padding for alignment)
    float* epre  = ws + 16;                     // EE*4
    float* xn    = epre + (size_t)EE * 4;       // BN
    float* hnb   = xn + BN;                     // HIDC*BN
    float* aggb  = hnb + (size_t)HIDC * BN;     // EOUTC*BN

    stats_kernel<<<1, 256, 0, stream>>>(ea, stats);
    edgepre_kernel<<<(EE + 255) / 256, 256, 0, stream>>>(ea, stats, epre);
    initxn_kernel<<<(BN + 255) / 256, 256, 0, stream>>>(pm, xn);
    hipMemsetAsync(hnb, 0, (size_t)HIDC * BN * sizeof(float), stream);

    for (int t = 0; t < PREDC; t++) {
        hipMemsetAsync(aggb, 0, (size_t)EOUTC * BN * sizeof(float), stream);
        edge_kernel<<<dim3((EE + 255) / 256, 2), 256, 0, stream>>>(
            xn, feat, t, eidx, epre, ew1, eb1, ew2, eb2, wmean, wstd, aggb);
        node_kernel<<<BN / 64, 256, 0, stream>>>(
            xn, feat, t, aggb, nw, nb, wi, wh, bi, bh, fw, fb, hnb, out);
    }
}

// Round 2
// 3431.287 us; speedup vs baseline: 7.0488x; 7.0488x over previous
//
#include <hip/hip_runtime.h>
#include <hip/hip_fp16.h>
#include <cstddef>

#define BB    4
#define NN    10000
#define EE    160000
#define BN    40000      // BB*NN
#define HISTC 8
#define PREDC 12
#define TSTEP 20         // HIST+PRED
#define FEX   8
#define HIDC  64
#define EHID  32
#define EOUTC 30
#define GOUTC 13
#define GINC  22         // GOUTC + 9

__device__ __forceinline__ float sigm(float x) {
    return 1.0f / (1.0f + __expf(-x));
}
__device__ __forceinline__ float tanh_fast(float x) {
    x = fminf(fmaxf(x, -15.0f), 15.0f);
    float e = __expf(2.0f * x);
    return (e - 1.0f) / (e + 1.0f);
}

// ---------------- edge_attr normalization stats (mean, 1/std ddof=1) ----------
__global__ void stats_kernel(const float* __restrict__ ea, float* __restrict__ stats) {
    __shared__ double sm[256][4];
    double s0 = 0, s1 = 0, q0 = 0, q1 = 0;
    for (int e = threadIdx.x; e < EE; e += 256) {
        float2 v = reinterpret_cast<const float2*>(ea)[e];
        double v0 = (double)v.x, v1 = (double)v.y;
        s0 += v0; q0 += v0 * v0;
        s1 += v1; q1 += v1 * v1;
    }
    sm[threadIdx.x][0] = s0; sm[threadIdx.x][1] = s1;
    sm[threadIdx.x][2] = q0; sm[threadIdx.x][3] = q1;
    __syncthreads();
    for (int off = 128; off > 0; off >>= 1) {
        if (threadIdx.x < off) {
            for (int k = 0; k < 4; k++) sm[threadIdx.x][k] += sm[threadIdx.x + off][k];
        }
        __syncthreads();
    }
    if (threadIdx.x == 0) {
        double m0 = sm[0][0] / EE, m1 = sm[0][1] / EE;
        double v0 = (sm[0][2] - sm[0][0] * sm[0][0] / EE) / (double)(EE - 1);
        double v1 = (sm[0][3] - sm[0][1] * sm[0][1] / EE) / (double)(EE - 1);
        float sd0 = fmaxf((float)sqrt(v0 > 0 ? v0 : 0.0), 1e-6f);
        float sd1 = fmaxf((float)sqrt(v1 > 0 ? v1 : 0.0), 1e-6f);
        stats[0] = (float)m0; stats[1] = (float)m1;
        stats[2] = 1.0f / sd0; stats[3] = 1.0f / sd1;
    }
}

// ---------------- per-edge precompute: ean0, ean1, dist, direc ----------------
__global__ void edgepre_kernel(const float* __restrict__ ea, const float* __restrict__ stats,
                               float* __restrict__ epre) {
    int e = blockIdx.x * 256 + threadIdx.x;
    if (e >= EE) return;
    float2 v = reinterpret_cast<const float2*>(ea)[e];
    float4 r;
    r.x = (v.x - stats[0]) * stats[2];
    r.y = (v.y - stats[1]) * stats[3];
    r.z = fmaxf(v.x, 1e-3f);   // city_dist
    r.w = v.y;                 // city_direc (raw)
    reinterpret_cast<float4*>(epre)[e] = r;
}

// ---------------- xn init from pm25_hist[:, -1] -------------------------------
__global__ void initxn_kernel(const float* __restrict__ pm, float* __restrict__ xn) {
    int i = blockIdx.x * 256 + threadIdx.x;
    if (i >= BN) return;
    int b = i / NN, n = i - b * NN;
    xn[i] = pm[(b * HISTC + (HISTC - 1)) * NN + n];
}

// ---------------- CSR build (once per call) -----------------------------------
__global__ void hist_kernel(const int* __restrict__ eidx,
                            int* __restrict__ deg_t, int* __restrict__ deg_s) {
    int e = blockIdx.x * 256 + threadIdx.x;
    if (e >= EE) return;
    atomicAdd(&deg_s[eidx[e]], 1);
    atomicAdd(&deg_t[eidx[EE + e]], 1);
}

__global__ __launch_bounds__(1024) void scan_kernel(
    const int* __restrict__ deg_t, const int* __restrict__ deg_s,
    int* __restrict__ off_t, int* __restrict__ off_s,
    int* __restrict__ cnt_t, int* __restrict__ cnt_s)
{
    __shared__ int pt[1024], ps[1024];
    int tid = threadIdx.x;
    int base = tid * 10;
    int st = 0, ss = 0;
    for (int k = 0; k < 10; k++) {
        int i = base + k;
        if (i < NN) { st += deg_t[i]; ss += deg_s[i]; }
    }
    pt[tid] = st; ps[tid] = ss;
    __syncthreads();
    for (int off = 1; off < 1024; off <<= 1) {
        int vt = (tid >= off) ? pt[tid - off] : 0;
        int vs = (tid >= off) ? ps[tid - off] : 0;
        __syncthreads();
        pt[tid] += vt; ps[tid] += vs;
        __syncthreads();
    }
    int ext = (tid == 0) ? 0 : pt[tid - 1];
    int exs = (tid == 0) ? 0 : ps[tid - 1];
    for (int k = 0; k < 10; k++) {
        int i = base + k;
        if (i < NN) {
            off_t[i] = ext; cnt_t[i] = ext;
            off_s[i] = exs; cnt_s[i] = exs;
            ext += deg_t[i]; exs += deg_s[i];
        }
    }
    if (tid == 0) { off_t[NN] = EE; off_s[NN] = EE; }
}

__global__ void fill_kernel(const int* __restrict__ eidx,
                            int* __restrict__ cnt_t, int* __restrict__ cnt_s,
                            int* __restrict__ list_t, int* __restrict__ list_s)
{
    int e = blockIdx.x * 256 + threadIdx.x;
    if (e >= EE) return;
    int s = eidx[e];
    int g = eidx[EE + e];
    int p = atomicAdd(&cnt_t[g], 1); list_t[p] = e;
    int q = atomicAdd(&cnt_s[s], 1); list_s[q] = e;
}

// ---------------- edge MLP (+ folded n_w) -> fp16 h3 rows ---------------------
// grid (EE/256, 2); blockIdx.y = bA; thread handles batches bA and bA+2.
__global__ __launch_bounds__(256) void edge_kernel(
    const float* __restrict__ xn, const float* __restrict__ feature, int t,
    const int* __restrict__ eidx, const float* __restrict__ epre,
    const float* __restrict__ ew1, const float* __restrict__ eb1,
    const float* __restrict__ ew2, const float* __restrict__ eb2,
    const float* __restrict__ nw,
    const float* __restrict__ wmean, const float* __restrict__ wstd,
    __half* __restrict__ h3)
{
    __shared__ alignas(16) float w1p[EHID * 24];       // [o][k] padded to 24
    __shared__ alignas(16) float w2t[EOUTC * EHID];    // [o][k]
    __shared__ float nws[EOUTC * GOUTC];               // [c][j]
    __shared__ float b1s[EHID];
    __shared__ float b2s[EOUTC];
    for (int i = threadIdx.x; i < EHID * 21; i += 256) {
        int o = i / 21, k = i - o * 21;
        w1p[o * 24 + k] = ew1[k * EHID + o];
    }
    if (threadIdx.x < EHID) {
        w1p[threadIdx.x * 24 + 21] = 0.f;
        w1p[threadIdx.x * 24 + 22] = 0.f;
        w1p[threadIdx.x * 24 + 23] = 0.f;
        b1s[threadIdx.x] = eb1[threadIdx.x];
    }
    for (int i = threadIdx.x; i < EOUTC * EHID; i += 256) {
        int o = i / EHID, k = i - o * EHID;
        w2t[i] = ew2[k * EOUTC + o];
    }
    for (int i = threadIdx.x; i < EOUTC * GOUTC; i += 256) nws[i] = nw[i];
    if (threadIdx.x < EOUTC) b2s[threadIdx.x] = eb2[threadIdx.x];
    __syncthreads();

    int e = blockIdx.x * 256 + threadIdx.x;
    if (e >= EE) return;
    int bA = blockIdx.y;
    int bB = bA + 2;
    int s = eidx[e];
    int g = eidx[EE + e];
    float4 ep = reinterpret_cast<const float4*>(epre)[e];
    float wm0 = wmean[0], wm1 = wmean[1];
    float sd0 = fmaxf(wstd[0], 1e-6f), sd1 = fmaxf(wstd[1], 1e-6f);

    float inA[21], inB[21];
    {
        const size_t fo = ((size_t)bA * TSTEP + HISTC + t) * NN;
        inA[0] = xn[bA * NN + s];
        const float4* fp = reinterpret_cast<const float4*>(feature + (fo + s) * FEX);
        float4 u = fp[0], v = fp[1];
        inA[1] = u.x; inA[2] = u.y; inA[3] = u.z; inA[4] = u.w;
        inA[5] = v.x; inA[6] = v.y; inA[7] = v.z; inA[8] = v.w;
        inA[9] = xn[bA * NN + g];
        const float4* fq = reinterpret_cast<const float4*>(feature + (fo + g) * FEX);
        float4 p = fq[0], q = fq[1];
        inA[10] = p.x; inA[11] = p.y; inA[12] = p.z; inA[13] = p.w;
        inA[14] = q.x; inA[15] = q.y; inA[16] = q.z; inA[17] = q.w;
    }
    {
        const size_t fo = ((size_t)bB * TSTEP + HISTC + t) * NN;
        inB[0] = xn[bB * NN + s];
        const float4* fp = reinterpret_cast<const float4*>(feature + (fo + s) * FEX);
        float4 u = fp[0], v = fp[1];
        inB[1] = u.x; inB[2] = u.y; inB[3] = u.z; inB[4] = u.w;
        inB[5] = v.x; inB[6] = v.y; inB[7] = v.z; inB[8] = v.w;
        inB[9] = xn[bB * NN + g];
        const float4* fq = reinterpret_cast<const float4*>(feature + (fo + g) * FEX);
        float4 p = fq[0], q = fq[1];
        inB[10] = p.x; inB[11] = p.y; inB[12] = p.z; inB[13] = p.w;
        inB[14] = q.x; inB[15] = q.y; inB[16] = q.z; inB[17] = q.w;
    }
    inA[18] = ep.x; inA[19] = ep.y;
    inB[18] = ep.x; inB[19] = ep.y;
    {
        float sp = fmaxf(inA[7] * sd0 + wm0, 0.f);
        float wd = (inA[8] * sd1 + wm1) * 0.017453292519943295f;
        float th = fabsf(ep.w - wd);
        inA[20] = fmaxf(3.f * sp * __cosf(th) / ep.z, 0.f);
    }
    {
        float sp = fmaxf(inB[7] * sd0 + wm0, 0.f);
        float wd = (inB[8] * sd1 + wm1) * 0.017453292519943295f;
        float th = fabsf(ep.w - wd);
        inB[20] = fmaxf(3.f * sp * __cosf(th) / ep.z, 0.f);
    }

    float h1A[EHID], h1B[EHID];
    #pragma unroll
    for (int o = 0; o < EHID; o++) {
        float a = b1s[o], b = b1s[o];
        const float4* wr = reinterpret_cast<const float4*>(&w1p[o * 24]);
        #pragma unroll
        for (int q = 0; q < 5; q++) {
            float4 w = wr[q];
            a += inA[4*q] * w.x + inA[4*q+1] * w.y + inA[4*q+2] * w.z + inA[4*q+3] * w.w;
            b += inB[4*q] * w.x + inB[4*q+1] * w.y + inB[4*q+2] * w.z + inB[4*q+3] * w.w;
        }
        float wl = w1p[o * 24 + 20];
        a += inA[20] * wl;
        b += inB[20] * wl;
        h1A[o] = sigm(a);
        h1B[o] = sigm(b);
    }

    float h3A[GOUTC], h3B[GOUTC];
    #pragma unroll
    for (int j = 0; j < GOUTC; j++) { h3A[j] = 0.f; h3B[j] = 0.f; }
    for (int o = 0; o < EOUTC; o++) {
        float a = b2s[o], b = b2s[o];
        const float4* wr = reinterpret_cast<const float4*>(&w2t[o * EHID]);
        #pragma unroll
        for (int q = 0; q < 8; q++) {
            float4 w = wr[q];
            a += h1A[4*q] * w.x + h1A[4*q+1] * w.y + h1A[4*q+2] * w.z + h1A[4*q+3] * w.w;
            b += h1B[4*q] * w.x + h1B[4*q+1] * w.y + h1B[4*q+2] * w.z + h1B[4*q+3] * w.w;
        }
        float vA = sigm(a), vB = sigm(b);
        #pragma unroll
        for (int j = 0; j < GOUTC; j++) {
            float w = nws[o * GOUTC + j];
            h3A[j] += vA * w;
            h3B[j] += vB * w;
        }
    }

    alignas(16) __half rA[16], rB[16];
    #pragma unroll
    for (int j = 0; j < GOUTC; j++) {
        rA[j] = __float2half(h3A[j]);
        rB[j] = __float2half(h3B[j]);
    }
    #pragma unroll
    for (int j = GOUTC; j < 16; j++) { rA[j] = __float2half(0.f); rB[j] = __float2half(0.f); }
    __half* outA = h3 + ((size_t)bA * EE + e) * 16;
    __half* outB = h3 + ((size_t)bB * EE + e) * 16;
    reinterpret_cast<uint4*>(outA)[0] = reinterpret_cast<const uint4*>(rA)[0];
    reinterpret_cast<uint4*>(outA)[1] = reinterpret_cast<const uint4*>(rA)[1];
    reinterpret_cast<uint4*>(outB)[0] = reinterpret_cast<const uint4*>(rB)[0];
    reinterpret_cast<uint4*>(outB)[1] = reinterpret_cast<const uint4*>(rB)[1];
}

// ---------------- gather: agg13[b][n][ch] = sum_in h3 - sum_out h3 ------------
// One wave per node: lane = b*16 + ch (4 batches x 16 channels).
__global__ __launch_bounds__(256) void gather_kernel(
    const __half* __restrict__ h3,
    const int* __restrict__ off_t, const int* __restrict__ list_t,
    const int* __restrict__ off_s, const int* __restrict__ list_s,
    float* __restrict__ agg)
{
    int n = (blockIdx.x * 256 + threadIdx.x) >> 6;
    if (n >= NN) return;
    int lane = threadIdx.x & 63;
    int b = lane >> 4, ch = lane & 15;
    const __half* hb = h3 + (size_t)b * EE * 16 + ch;
    float acc = 0.f;
    int i1 = off_t[n + 1];
    for (int i = off_t[n]; i < i1; i++) {
        int e = list_t[i];
        acc += __half2float(hb[(size_t)e * 16]);
    }
    i1 = off_s[n + 1];
    for (int i = off_s[n]; i < i1; i++) {
        int e = list_s[i];
        acc -= __half2float(hb[(size_t)e * 16]);
    }
    agg[((size_t)b * NN + n) * 16 + ch] = acc;
}

// ---------------- node: gnn-out + GRU + fc ------------------------------------
__global__ __launch_bounds__(256) void node_kernel(
    float* xnio, const float* __restrict__ feature, int t,
    const float* __restrict__ agg, const float* __restrict__ nb,
    const float* __restrict__ wi, const float* __restrict__ wh,
    const float* __restrict__ bi, const float* __restrict__ bh,
    const float* __restrict__ fw, const float* __restrict__ fb,
    float* __restrict__ hnbuf, float* __restrict__ out)
{
    __shared__ float xpart[4][64];
    int lane = threadIdx.x & 63;
    int wav  = threadIdx.x >> 6;
    int node = blockIdx.x * 64 + lane;
    int b = node / NN;
    int n = node - b * NN;

    float xc[GINC];
    {
        const float4* ar = reinterpret_cast<const float4*>(agg + (size_t)node * 16);
        float4 a0 = ar[0], a1 = ar[1], a2 = ar[2];
        float a3 = agg[(size_t)node * 16 + 12];
        xc[0] = sigm(a0.x + nb[0]);  xc[1] = sigm(a0.y + nb[1]);
        xc[2] = sigm(a0.z + nb[2]);  xc[3] = sigm(a0.w + nb[3]);
        xc[4] = sigm(a1.x + nb[4]);  xc[5] = sigm(a1.y + nb[5]);
        xc[6] = sigm(a1.z + nb[6]);  xc[7] = sigm(a1.w + nb[7]);
        xc[8] = sigm(a2.x + nb[8]);  xc[9] = sigm(a2.y + nb[9]);
        xc[10] = sigm(a2.z + nb[10]); xc[11] = sigm(a2.w + nb[11]);
        xc[12] = sigm(a3 + nb[12]);
    }
    xc[13] = xnio[node];
    {
        const float4* fp = reinterpret_cast<const float4*>(
            feature + (((size_t)b * TSTEP + HISTC + t) * NN + n) * FEX);
        float4 u = fp[0], v = fp[1];
        xc[14] = u.x; xc[15] = u.y; xc[16] = u.z; xc[17] = u.w;
        xc[18] = v.x; xc[19] = v.y; xc[20] = v.z; xc[21] = v.w;
    }

    float h[HIDC];
    #pragma unroll
    for (int k = 0; k < HIDC; k++) h[k] = hnbuf[(size_t)k * BN + node];
    __syncthreads();

    float xsum = 0.f;
    for (int jj = 0; jj < 16; jj++) {
        int j = wav * 16 + jj;   // wave-uniform
        float ir = bi[j], iz = bi[64 + j], in_ = bi[128 + j];
        const float* wr0 = wi + (size_t)j * GINC;
        const float* wr1 = wi + (size_t)(64 + j) * GINC;
        const float* wr2 = wi + (size_t)(128 + j) * GINC;
        #pragma unroll
        for (int k = 0; k < GINC; k++) {
            ir  += wr0[k] * xc[k];
            iz  += wr1[k] * xc[k];
            in_ += wr2[k] * xc[k];
        }
        float hr = bh[j], hz = bh[64 + j], hn_ = bh[128 + j];
        const float* vr0 = wh + (size_t)j * HIDC;
        const float* vr1 = wh + (size_t)(64 + j) * HIDC;
        const float* vr2 = wh + (size_t)(128 + j) * HIDC;
        #pragma unroll
        for (int k = 0; k < HIDC; k++) {
            hr  += vr0[k] * h[k];
            hz  += vr1[k] * h[k];
            hn_ += vr2[k] * h[k];
        }
        float r  = sigm(ir + hr);
        float z  = sigm(iz + hz);
        float nn = tanh_fast(in_ + r * hn_);
        float hold = h[j];
        float hnew = (1.f - z) * nn + z * hold;
        hnbuf[(size_t)j * BN + node] = hnew;
        xsum += hnew * fw[j];
    }
    xpart[wav][lane] = xsum;
    __syncthreads();
    if (wav == 0) {
        float tot = xpart[0][lane] + xpart[1][lane] + xpart[2][lane] + xpart[3][lane] + fb[0];
        xnio[node] = tot;
        out[(size_t)node * PREDC + t] = tot;
    }
}

extern "C" void kernel_launch(void* const* d_in, const int* in_sizes, int n_in,
                              void* d_out, int out_size, void* d_ws, size_t ws_size,
                              hipStream_t stream)
{
    const float* pm    = (const float*)d_in[0];
    const float* feat  = (const float*)d_in[1];
    const float* ea    = (const float*)d_in[2];
    const float* wmean = (const float*)d_in[3];
    const float* wstd  = (const float*)d_in[4];
    const float* ew1   = (const float*)d_in[5];
    const float* eb1   = (const float*)d_in[6];
    const float* ew2   = (const float*)d_in[7];
    const float* eb2   = (const float*)d_in[8];
    const float* nw    = (const float*)d_in[9];
    const float* nb    = (const float*)d_in[10];
    const float* wi    = (const float*)d_in[11];
    const float* wh    = (const float*)d_in[12];
    const float* bi    = (const float*)d_in[13];
    const float* bh    = (const float*)d_in[14];
    const float* fw    = (const float*)d_in[15];
    const float* fb    = (const float*)d_in[16];
    const int*   eidx  = (const int*)d_in[17];
    float* out = (float*)d_out;
    float* ws  = (float*)d_ws;

    float*  stats = ws;                              // 16 floats
    float*  epre  = ws + 16;                         // EE*4
    float*  xn    = epre + (size_t)EE * 4;           // BN
    float*  hnb   = xn + BN;                         // HIDC*BN
    float*  agg13 = hnb + (size_t)HIDC * BN;         // BN*16
    __half* h3b   = (__half*)(agg13 + (size_t)BN * 16);   // BB*EE*16 halfs
    int*    deg_t = (int*)(h3b + (size_t)BB * EE * 16);   // NN
    int*    deg_s = deg_t + NN;                      // NN
    int*    off_t = deg_s + NN;                      // NN+1
    int*    off_s = off_t + NN + 1;                  // NN+1
    int*    cnt_t = off_s + NN + 1;                  // NN
    int*    cnt_s = cnt_t + NN;                      // NN
    int*    list_t = cnt_s + NN;                     // EE
    int*    list_s = list_t + EE;                    // EE

    stats_kernel<<<1, 256, 0, stream>>>(ea, stats);
    edgepre_kernel<<<(EE + 255) / 256, 256, 0, stream>>>(ea, stats, epre);
    initxn_kernel<<<(BN + 255) / 256, 256, 0, stream>>>(pm, xn);
    hipMemsetAsync(hnb, 0, (size_t)HIDC * BN * sizeof(float), stream);
    hipMemsetAsync(deg_t, 0, 2 * NN * sizeof(int), stream);
    hist_kernel<<<(EE + 255) / 256, 256, 0, stream>>>(eidx, deg_t, deg_s);
    scan_kernel<<<1, 1024, 0, stream>>>(deg_t, deg_s, off_t, off_s, cnt_t, cnt_s);
    fill_kernel<<<(EE + 255) / 256, 256, 0, stream>>>(eidx, cnt_t, cnt_s, list_t, list_s);

    for (int t = 0; t < PREDC; t++) {
        edge_kernel<<<dim3((EE + 255) / 256, 2), 256, 0, stream>>>(
            xn, feat, t, eidx, epre, ew1, eb1, ew2, eb2, nw, wmean, wstd, h3b);
        gather_kernel<<<(NN * 64 + 255) / 256, 256, 0, stream>>>(
            h3b, off_t, list_t, off_s, list_s, agg13);
        node_kernel<<<BN / 64, 256, 0, stream>>>(
            xn, feat, t, agg13, nb, wi, wh, bi, bh, fw, fb, hnb, out);
    }
}

// Round 3
// 2216.360 us; speedup vs baseline: 10.9127x; 1.5482x over previous
//
#include <hip/hip_runtime.h>
#include <hip/hip_fp16.h>
#include <cstddef>

#define BB    4
#define NN    10000
#define EE    160000
#define BN    40000      // BB*NN
#define HISTC 8
#define PREDC 12
#define TSTEP 20         // HIST+PRED
#define FEX   8
#define HIDC  64
#define EHID  32
#define EOUTC 30
#define GOUTC 13
#define GINC  22         // GOUTC + 9

__device__ __forceinline__ float sigm(float x) {
    return 1.0f / (1.0f + __expf(-x));
}
__device__ __forceinline__ float tanh_fast(float x) {
    x = fminf(fmaxf(x, -15.0f), 15.0f);
    float e = __expf(2.0f * x);
    return (e - 1.0f) / (e + 1.0f);
}

// ---------------- edge_attr stats: stage 1 (per-block partials) ---------------
__global__ __launch_bounds__(256) void stats1_kernel(const float* __restrict__ ea,
                                                     double* __restrict__ part) {
    __shared__ double sm[256][4];
    int tid = threadIdx.x;
    double s0 = 0, s1 = 0, q0 = 0, q1 = 0;
    for (int e = blockIdx.x * 256 + tid; e < EE; e += 256 * 256) {
        float2 v = reinterpret_cast<const float2*>(ea)[e];
        double v0 = (double)v.x, v1 = (double)v.y;
        s0 += v0; q0 += v0 * v0;
        s1 += v1; q1 += v1 * v1;
    }
    sm[tid][0] = s0; sm[tid][1] = s1; sm[tid][2] = q0; sm[tid][3] = q1;
    __syncthreads();
    for (int off = 128; off > 0; off >>= 1) {
        if (tid < off)
            for (int k = 0; k < 4; k++) sm[tid][k] += sm[tid + off][k];
        __syncthreads();
    }
    if (tid == 0) {
        part[blockIdx.x * 4 + 0] = sm[0][0];
        part[blockIdx.x * 4 + 1] = sm[0][1];
        part[blockIdx.x * 4 + 2] = sm[0][2];
        part[blockIdx.x * 4 + 3] = sm[0][3];
    }
}

// ---------------- stats stage 2: reduce 256 partials, emit mean / inv-std -----
__global__ __launch_bounds__(256) void stats2_kernel(const double* __restrict__ part,
                                                     float* __restrict__ stats) {
    __shared__ double sm[256][4];
    int tid = threadIdx.x;
    sm[tid][0] = part[tid * 4 + 0];
    sm[tid][1] = part[tid * 4 + 1];
    sm[tid][2] = part[tid * 4 + 2];
    sm[tid][3] = part[tid * 4 + 3];
    __syncthreads();
    for (int off = 128; off > 0; off >>= 1) {
        if (tid < off)
            for (int k = 0; k < 4; k++) sm[tid][k] += sm[tid + off][k];
        __syncthreads();
    }
    if (tid == 0) {
        double m0 = sm[0][0] / EE, m1 = sm[0][1] / EE;
        double v0 = (sm[0][2] - sm[0][0] * sm[0][0] / EE) / (double)(EE - 1);
        double v1 = (sm[0][3] - sm[0][1] * sm[0][1] / EE) / (double)(EE - 1);
        float sd0 = fmaxf((float)sqrt(v0 > 0 ? v0 : 0.0), 1e-6f);
        float sd1 = fmaxf((float)sqrt(v1 > 0 ? v1 : 0.0), 1e-6f);
        stats[0] = (float)m0; stats[1] = (float)m1;
        stats[2] = 1.0f / sd0; stats[3] = 1.0f / sd1;
    }
}

// ---------------- per-edge precompute: ean0, ean1, dist, direc ----------------
__global__ void edgepre_kernel(const float* __restrict__ ea, const float* __restrict__ stats,
                               float* __restrict__ epre) {
    int e = blockIdx.x * 256 + threadIdx.x;
    if (e >= EE) return;
    float2 v = reinterpret_cast<const float2*>(ea)[e];
    float4 r;
    r.x = (v.x - stats[0]) * stats[2];
    r.y = (v.y - stats[1]) * stats[3];
    r.z = fmaxf(v.x, 1e-3f);   // city_dist
    r.w = v.y;                 // city_direc (raw)
    reinterpret_cast<float4*>(epre)[e] = r;
}

// ---------------- xn init from pm25_hist[:, -1] -------------------------------
__global__ void initxn_kernel(const float* __restrict__ pm, float* __restrict__ xn) {
    int i = blockIdx.x * 256 + threadIdx.x;
    if (i >= BN) return;
    int b = i / NN, n = i - b * NN;
    xn[i] = pm[(b * HISTC + (HISTC - 1)) * NN + n];
}

// ---------------- CSR build (once per call) -----------------------------------
__global__ void hist_kernel(const int* __restrict__ eidx,
                            int* __restrict__ deg_t, int* __restrict__ deg_s) {
    int e = blockIdx.x * 256 + threadIdx.x;
    if (e >= EE) return;
    atomicAdd(&deg_s[eidx[e]], 1);
    atomicAdd(&deg_t[eidx[EE + e]], 1);
}

__global__ __launch_bounds__(1024) void scan_kernel(
    const int* __restrict__ deg_t, const int* __restrict__ deg_s,
    int* __restrict__ off_t, int* __restrict__ off_s,
    int* __restrict__ cnt_t, int* __restrict__ cnt_s)
{
    __shared__ int pt[1024], ps[1024];
    int tid = threadIdx.x;
    int base = tid * 10;
    int st = 0, ss = 0;
    for (int k = 0; k < 10; k++) {
        int i = base + k;
        if (i < NN) { st += deg_t[i]; ss += deg_s[i]; }
    }
    pt[tid] = st; ps[tid] = ss;
    __syncthreads();
    for (int off = 1; off < 1024; off <<= 1) {
        int vt = (tid >= off) ? pt[tid - off] : 0;
        int vs = (tid >= off) ? ps[tid - off] : 0;
        __syncthreads();
        pt[tid] += vt; ps[tid] += vs;
        __syncthreads();
    }
    int ext = (tid == 0) ? 0 : pt[tid - 1];
    int exs = (tid == 0) ? 0 : ps[tid - 1];
    for (int k = 0; k < 10; k++) {
        int i = base + k;
        if (i < NN) {
            off_t[i] = ext; cnt_t[i] = ext;
            off_s[i] = exs; cnt_s[i] = exs;
            ext += deg_t[i]; exs += deg_s[i];
        }
    }
    if (tid == 0) { off_t[NN] = EE; off_s[NN] = EE; }
}

// pos_t[e] = slot of edge e in tgt-CSR order; pos_s[e] = slot in src-CSR order
__global__ void fill_kernel(const int* __restrict__ eidx,
                            int* __restrict__ cnt_t, int* __restrict__ cnt_s,
                            int* __restrict__ pos_t, int* __restrict__ pos_s)
{
    int e = blockIdx.x * 256 + threadIdx.x;
    if (e >= EE) return;
    int s = eidx[e];
    int g = eidx[EE + e];
    pos_t[e] = atomicAdd(&cnt_t[g], 1);
    pos_s[e] = atomicAdd(&cnt_s[s], 1);
}

// ---------------- edge MLP (+ folded n_w) -> fp16 h3 rows in CSR slot order ---
// grid (EE/256, 2); blockIdx.y = bA; thread handles batches bA and bA+2.
// Writes each row twice: into h3t at pos_t[e] and h3s at pos_s[e] so the
// gather kernel reads contiguously.
__global__ __launch_bounds__(256) void edge_kernel(
    const float* __restrict__ xn, const float* __restrict__ feature, int t,
    const int* __restrict__ eidx, const float* __restrict__ epre,
    const int* __restrict__ pos_t, const int* __restrict__ pos_s,
    const float* __restrict__ ew1, const float* __restrict__ eb1,
    const float* __restrict__ ew2, const float* __restrict__ eb2,
    const float* __restrict__ nw,
    const float* __restrict__ wmean, const float* __restrict__ wstd,
    __half* __restrict__ h3t, __half* __restrict__ h3s)
{
    __shared__ alignas(16) float w1p[EHID * 24];       // [o][k] padded to 24
    __shared__ alignas(16) float w2t[EOUTC * EHID];    // [o][k]
    __shared__ float nws[EOUTC * GOUTC];               // [c][j]
    __shared__ float b1s[EHID];
    __shared__ float b2s[EOUTC];
    for (int i = threadIdx.x; i < EHID * 21; i += 256) {
        int o = i / 21, k = i - o * 21;
        w1p[o * 24 + k] = ew1[k * EHID + o];
    }
    if (threadIdx.x < EHID) {
        w1p[threadIdx.x * 24 + 21] = 0.f;
        w1p[threadIdx.x * 24 + 22] = 0.f;
        w1p[threadIdx.x * 24 + 23] = 0.f;
        b1s[threadIdx.x] = eb1[threadIdx.x];
    }
    for (int i = threadIdx.x; i < EOUTC * EHID; i += 256) {
        int o = i / EHID, k = i - o * EHID;
        w2t[i] = ew2[k * EOUTC + o];
    }
    for (int i = threadIdx.x; i < EOUTC * GOUTC; i += 256) nws[i] = nw[i];
    if (threadIdx.x < EOUTC) b2s[threadIdx.x] = eb2[threadIdx.x];
    __syncthreads();

    int e = blockIdx.x * 256 + threadIdx.x;
    if (e >= EE) return;
    int bA = blockIdx.y;
    int bB = bA + 2;
    int s = eidx[e];
    int g = eidx[EE + e];
    int pt = pos_t[e];
    int ps = pos_s[e];
    float4 ep = reinterpret_cast<const float4*>(epre)[e];
    float wm0 = wmean[0], wm1 = wmean[1];
    float sd0 = fmaxf(wstd[0], 1e-6f), sd1 = fmaxf(wstd[1], 1e-6f);

    float inA[21], inB[21];
    {
        const size_t fo = ((size_t)bA * TSTEP + HISTC + t) * NN;
        inA[0] = xn[bA * NN + s];
        const float4* fp = reinterpret_cast<const float4*>(feature + (fo + s) * FEX);
        float4 u = fp[0], v = fp[1];
        inA[1] = u.x; inA[2] = u.y; inA[3] = u.z; inA[4] = u.w;
        inA[5] = v.x; inA[6] = v.y; inA[7] = v.z; inA[8] = v.w;
        inA[9] = xn[bA * NN + g];
        const float4* fq = reinterpret_cast<const float4*>(feature + (fo + g) * FEX);
        float4 p = fq[0], q = fq[1];
        inA[10] = p.x; inA[11] = p.y; inA[12] = p.z; inA[13] = p.w;
        inA[14] = q.x; inA[15] = q.y; inA[16] = q.z; inA[17] = q.w;
    }
    {
        const size_t fo = ((size_t)bB * TSTEP + HISTC + t) * NN;
        inB[0] = xn[bB * NN + s];
        const float4* fp = reinterpret_cast<const float4*>(feature + (fo + s) * FEX);
        float4 u = fp[0], v = fp[1];
        inB[1] = u.x; inB[2] = u.y; inB[3] = u.z; inB[4] = u.w;
        inB[5] = v.x; inB[6] = v.y; inB[7] = v.z; inB[8] = v.w;
        inB[9] = xn[bB * NN + g];
        const float4* fq = reinterpret_cast<const float4*>(feature + (fo + g) * FEX);
        float4 p = fq[0], q = fq[1];
        inB[10] = p.x; inB[11] = p.y; inB[12] = p.z; inB[13] = p.w;
        inB[14] = q.x; inB[15] = q.y; inB[16] = q.z; inB[17] = q.w;
    }
    inA[18] = ep.x; inA[19] = ep.y;
    inB[18] = ep.x; inB[19] = ep.y;
    {
        float sp = fmaxf(inA[7] * sd0 + wm0, 0.f);
        float wd = (inA[8] * sd1 + wm1) * 0.017453292519943295f;
        float th = fabsf(ep.w - wd);
        inA[20] = fmaxf(3.f * sp * __cosf(th) / ep.z, 0.f);
    }
    {
        float sp = fmaxf(inB[7] * sd0 + wm0, 0.f);
        float wd = (inB[8] * sd1 + wm1) * 0.017453292519943295f;
        float th = fabsf(ep.w - wd);
        inB[20] = fmaxf(3.f * sp * __cosf(th) / ep.z, 0.f);
    }

    float h1A[EHID], h1B[EHID];
    #pragma unroll
    for (int o = 0; o < EHID; o++) {
        float a = b1s[o], b = b1s[o];
        const float4* wr = reinterpret_cast<const float4*>(&w1p[o * 24]);
        #pragma unroll
        for (int q = 0; q < 5; q++) {
            float4 w = wr[q];
            a += inA[4*q] * w.x + inA[4*q+1] * w.y + inA[4*q+2] * w.z + inA[4*q+3] * w.w;
            b += inB[4*q] * w.x + inB[4*q+1] * w.y + inB[4*q+2] * w.z + inB[4*q+3] * w.w;
        }
        float wl = w1p[o * 24 + 20];
        a += inA[20] * wl;
        b += inB[20] * wl;
        h1A[o] = sigm(a);
        h1B[o] = sigm(b);
    }

    float h3A[GOUTC], h3B[GOUTC];
    #pragma unroll
    for (int j = 0; j < GOUTC; j++) { h3A[j] = 0.f; h3B[j] = 0.f; }
    for (int o = 0; o < EOUTC; o++) {
        float a = b2s[o], b = b2s[o];
        const float4* wr = reinterpret_cast<const float4*>(&w2t[o * EHID]);
        #pragma unroll
        for (int q = 0; q < 8; q++) {
            float4 w = wr[q];
            a += h1A[4*q] * w.x + h1A[4*q+1] * w.y + h1A[4*q+2] * w.z + h1A[4*q+3] * w.w;
            b += h1B[4*q] * w.x + h1B[4*q+1] * w.y + h1B[4*q+2] * w.z + h1B[4*q+3] * w.w;
        }
        float vA = sigm(a), vB = sigm(b);
        #pragma unroll
        for (int j = 0; j < GOUTC; j++) {
            float w = nws[o * GOUTC + j];
            h3A[j] += vA * w;
            h3B[j] += vB * w;
        }
    }

    alignas(16) __half rA[16], rB[16];
    #pragma unroll
    for (int j = 0; j < GOUTC; j++) {
        rA[j] = __float2half(h3A[j]);
        rB[j] = __float2half(h3B[j]);
    }
    #pragma unroll
    for (int j = GOUTC; j < 16; j++) { rA[j] = __float2half(0.f); rB[j] = __float2half(0.f); }
    uint4 rA0 = reinterpret_cast<const uint4*>(rA)[0];
    uint4 rA1 = reinterpret_cast<const uint4*>(rA)[1];
    uint4 rB0 = reinterpret_cast<const uint4*>(rB)[0];
    uint4 rB1 = reinterpret_cast<const uint4*>(rB)[1];
    {
        __half* oA = h3t + ((size_t)bA * EE + pt) * 16;
        __half* oB = h3t + ((size_t)bB * EE + pt) * 16;
        reinterpret_cast<uint4*>(oA)[0] = rA0;
        reinterpret_cast<uint4*>(oA)[1] = rA1;
        reinterpret_cast<uint4*>(oB)[0] = rB0;
        reinterpret_cast<uint4*>(oB)[1] = rB1;
    }
    {
        __half* oA = h3s + ((size_t)bA * EE + ps) * 16;
        __half* oB = h3s + ((size_t)bB * EE + ps) * 16;
        reinterpret_cast<uint4*>(oA)[0] = rA0;
        reinterpret_cast<uint4*>(oA)[1] = rA1;
        reinterpret_cast<uint4*>(oB)[0] = rB0;
        reinterpret_cast<uint4*>(oB)[1] = rB1;
    }
}

// ---------------- gather: agg13[b][n][ch] = sum_in h3t - sum_out h3s ----------
// One wave per node: lane = b*16 + ch. Reads are CONTIGUOUS slot ranges.
__global__ __launch_bounds__(256) void gather_kernel(
    const __half* __restrict__ h3t, const __half* __restrict__ h3s,
    const int* __restrict__ off_t, const int* __restrict__ off_s,
    float* __restrict__ agg)
{
    int n = (blockIdx.x * 256 + threadIdx.x) >> 6;
    if (n >= NN) return;
    n = __builtin_amdgcn_readfirstlane(n);
    int lane = threadIdx.x & 63;
    int b = lane >> 4, ch = lane & 15;
    const __half* ht = h3t + (size_t)b * EE * 16 + ch;
    const __half* hs = h3s + (size_t)b * EE * 16 + ch;
    float acc = 0.f;
    int i0 = off_t[n], i1 = off_t[n + 1];
    for (int i = i0; i < i1; i++) {
        acc += __half2float(ht[(size_t)i * 16]);
    }
    i0 = off_s[n]; i1 = off_s[n + 1];
    for (int i = i0; i < i1; i++) {
        acc -= __half2float(hs[(size_t)i * 16]);
    }
    agg[((size_t)b * NN + n) * 16 + ch] = acc;
}

// ---------------- node: gnn-out + GRU + fc ------------------------------------
// grid BN/64 blocks of 256: each block = 64 nodes; wave w handles hidden dims
// [w*16, w*16+16). j forced wave-uniform via readfirstlane -> s_load weights.
__global__ __launch_bounds__(256) void node_kernel(
    float* xnio, const float* __restrict__ feature, int t,
    const float* __restrict__ agg, const float* __restrict__ nb,
    const float* __restrict__ wi, const float* __restrict__ wh,
    const float* __restrict__ bi, const float* __restrict__ bh,
    const float* __restrict__ fw, const float* __restrict__ fb,
    float* __restrict__ hnbuf, float* __restrict__ out)
{
    __shared__ float xpart[4][64];
    int lane = threadIdx.x & 63;
    int wav  = threadIdx.x >> 6;
    int node = blockIdx.x * 64 + lane;
    int b = node / NN;
    int n = node - b * NN;

    float xc[GINC];
    {
        const float4* ar = reinterpret_cast<const float4*>(agg + (size_t)node * 16);
        float4 a0 = ar[0], a1 = ar[1], a2 = ar[2];
        float a3 = agg[(size_t)node * 16 + 12];
        xc[0] = sigm(a0.x + nb[0]);  xc[1] = sigm(a0.y + nb[1]);
        xc[2] = sigm(a0.z + nb[2]);  xc[3] = sigm(a0.w + nb[3]);
        xc[4] = sigm(a1.x + nb[4]);  xc[5] = sigm(a1.y + nb[5]);
        xc[6] = sigm(a1.z + nb[6]);  xc[7] = sigm(a1.w + nb[7]);
        xc[8] = sigm(a2.x + nb[8]);  xc[9] = sigm(a2.y + nb[9]);
        xc[10] = sigm(a2.z + nb[10]); xc[11] = sigm(a2.w + nb[11]);
        xc[12] = sigm(a3 + nb[12]);
    }
    xc[13] = xnio[node];
    {
        const float4* fp = reinterpret_cast<const float4*>(
            feature + (((size_t)b * TSTEP + HISTC + t) * NN + n) * FEX);
        float4 u = fp[0], v = fp[1];
        xc[14] = u.x; xc[15] = u.y; xc[16] = u.z; xc[17] = u.w;
        xc[18] = v.x; xc[19] = v.y; xc[20] = v.z; xc[21] = v.w;
    }

    float h[HIDC];
    #pragma unroll
    for (int k = 0; k < HIDC; k++) h[k] = hnbuf[(size_t)k * BN + node];
    __syncthreads();

    float xsum = 0.f;
    for (int jj = 0; jj < 16; jj++) {
        int j = __builtin_amdgcn_readfirstlane(wav * 16 + jj);  // wave-uniform -> s_load
        float ir = bi[j], iz = bi[64 + j], in_ = bi[128 + j];
        const float* wr0 = wi + (size_t)j * GINC;
        const float* wr1 = wi + (size_t)(64 + j) * GINC;
        const float* wr2 = wi + (size_t)(128 + j) * GINC;
        #pragma unroll
        for (int k = 0; k < GINC; k++) {
            ir  += wr0[k] * xc[k];
            iz  += wr1[k] * xc[k];
            in_ += wr2[k] * xc[k];
        }
        float hr = bh[j], hz = bh[64 + j], hn_ = bh[128 + j];
        const float* vr0 = wh + (size_t)j * HIDC;
        const float* vr1 = wh + (size_t)(64 + j) * HIDC;
        const float* vr2 = wh + (size_t)(128 + j) * HIDC;
        #pragma unroll
        for (int k = 0; k < HIDC; k++) {
            hr  += vr0[k] * h[k];
            hz  += vr1[k] * h[k];
            hn_ += vr2[k] * h[k];
        }
        float r  = sigm(ir + hr);
        float z  = sigm(iz + hz);
        float nn = tanh_fast(in_ + r * hn_);
        float hold = hnbuf[(size_t)j * BN + node];  // L1 hit; avoids dyn VGPR index
        float hnew = (1.f - z) * nn + z * hold;
        hnbuf[(size_t)j * BN + node] = hnew;
        xsum += hnew * fw[j];
    }
    xpart[wav][lane] = xsum;
    __syncthreads();
    if (wav == 0) {
        float tot = xpart[0][lane] + xpart[1][lane] + xpart[2][lane] + xpart[3][lane] + fb[0];
        xnio[node] = tot;
        out[(size_t)node * PREDC + t] = tot;
    }
}

extern "C" void kernel_launch(void* const* d_in, const int* in_sizes, int n_in,
                              void* d_out, int out_size, void* d_ws, size_t ws_size,
                              hipStream_t stream)
{
    const float* pm    = (const float*)d_in[0];
    const float* feat  = (const float*)d_in[1];
    const float* ea    = (const float*)d_in[2];
    const float* wmean = (const float*)d_in[3];
    const float* wstd  = (const float*)d_in[4];
    const float* ew1   = (const float*)d_in[5];
    const float* eb1   = (const float*)d_in[6];
    const float* ew2   = (const float*)d_in[7];
    const float* eb2   = (const float*)d_in[8];
    const float* nw    = (const float*)d_in[9];
    const float* nb    = (const float*)d_in[10];
    const float* wi    = (const float*)d_in[11];
    const float* wh    = (const float*)d_in[12];
    const float* bi    = (const float*)d_in[13];
    const float* bh    = (const float*)d_in[14];
    const float* fw    = (const float*)d_in[15];
    const float* fb    = (const float*)d_in[16];
    const int*   eidx  = (const int*)d_in[17];
    float* out = (float*)d_out;

    char* w = (char*)d_ws;
    double* partd = (double*)w;                    w += 256 * 4 * sizeof(double);
    float*  stats = (float*)w;                     w += 16 * sizeof(float);
    float*  epre  = (float*)w;                     w += (size_t)EE * 4 * sizeof(float);
    float*  xn    = (float*)w;                     w += (size_t)BN * sizeof(float);
    float*  hnb   = (float*)w;                     w += (size_t)HIDC * BN * sizeof(float);
    float*  agg13 = (float*)w;                     w += (size_t)BN * 16 * sizeof(float);
    __half* h3t   = (__half*)w;                    w += (size_t)BB * EE * 16 * sizeof(__half);
    __half* h3s   = (__half*)w;                    w += (size_t)BB * EE * 16 * sizeof(__half);
    int*    deg_t = (int*)w;                       w += NN * sizeof(int);
    int*    deg_s = (int*)w;                       w += NN * sizeof(int);
    int*    off_t = (int*)w;                       w += (NN + 1) * sizeof(int);
    int*    off_s = (int*)w;                       w += (NN + 1) * sizeof(int);
    int*    cnt_t = (int*)w;                       w += NN * sizeof(int);
    int*    cnt_s = (int*)w;                       w += NN * sizeof(int);
    int*    pos_t = (int*)w;                       w += (size_t)EE * sizeof(int);
    int*    pos_s = (int*)w;                       w += (size_t)EE * sizeof(int);

    stats1_kernel<<<256, 256, 0, stream>>>(ea, partd);
    stats2_kernel<<<1, 256, 0, stream>>>(partd, stats);
    edgepre_kernel<<<(EE + 255) / 256, 256, 0, stream>>>(ea, stats, epre);
    initxn_kernel<<<(BN + 255) / 256, 256, 0, stream>>>(pm, xn);
    hipMemsetAsync(hnb, 0, (size_t)HIDC * BN * sizeof(float), stream);
    hipMemsetAsync(deg_t, 0, 2 * NN * sizeof(int), stream);
    hist_kernel<<<(EE + 255) / 256, 256, 0, stream>>>(eidx, deg_t, deg_s);
    scan_kernel<<<1, 1024, 0, stream>>>(deg_t, deg_s, off_t, off_s, cnt_t, cnt_s);
    fill_kernel<<<(EE + 255) / 256, 256, 0, stream>>>(eidx, cnt_t, cnt_s, pos_t, pos_s);

    for (int t = 0; t < PREDC; t++) {
        edge_kernel<<<dim3((EE + 255) / 256, 2), 256, 0, stream>>>(
            xn, feat, t, eidx, epre, pos_t, pos_s, ew1, eb1, ew2, eb2, nw,
            wmean, wstd, h3t, h3s);
        gather_kernel<<<(NN * 64 + 255) / 256, 256, 0, stream>>>(
            h3t, h3s, off_t, off_s, agg13);
        node_kernel<<<BN / 64, 256, 0, stream>>>(
            xn, feat, t, agg13, nb, wi, wh, bi, bh, fw, fb, hnb, out);
    }
}